// Round 15
// baseline (124.485 us; speedup 1.0000x reference)
//
#include <hip/hip_runtime.h>
#include <stdint.h>

#define S_LEN 4096
#define D_DIM 2048
#define NT 16
#define TD 128
#define KW 4
#define CTX 640
#define HID 256

typedef __bf16 bf16_t;
typedef __bf16 bf16x8 __attribute__((ext_vector_type(8)));
typedef __bf16 bf16x4 __attribute__((ext_vector_type(4)));
typedef float f32x4 __attribute__((ext_vector_type(4)));
typedef unsigned int u32;
typedef u32 __attribute__((address_space(1))) gu32;
typedef u32 __attribute__((address_space(3))) lu32;

__device__ __forceinline__ void gload_lds16(const void* g, void* l) {
    __builtin_amdgcn_global_load_lds((const gu32*)g, (lu32*)l, 16, 0, 0);
}

// ---------------- Kernel 1 (merged): blocks 0..511 = row stats + tile-sum
// partials; blocks 512..1279 = W1/W2 pre-tile/pre-swizzle.
__global__ __launch_bounds__(256) void k_pre(const float* __restrict__ x,
        const float* __restrict__ W1, const float* __restrict__ W2,
        float* __restrict__ partial, bf16_t* __restrict__ W1t, bf16_t* __restrict__ W2t)
{
    if (blockIdx.x >= 512) {   // ---- prep part ----
        const int g = (blockIdx.x - 512) * 256 + threadIdx.x;
        if (g < 10*256*64) {
            const int ks = g >> 14, rem = g & 16383, n = rem >> 6, kk = rem & 63;
            const int kkl = ((kk << 1) ^ ((n & 7) << 4)) >> 1;
            W1t[g] = (bf16_t)W1[n*CTX + ks*64 + kkl];
        } else if (g < 10*256*64 + 4*128*64) {
            const int gg = g - 10*256*64;
            const int ks = gg >> 13, rem = gg & 8191, n = rem >> 6, kk = rem & 63;
            const int kkl = ((kk << 1) ^ ((n & 7) << 4)) >> 1;
            W2t[gg] = (bf16_t)W2[n*HID + ks*64 + kkl];
        }
        return;
    }
    // ---- stats part ----
    __shared__ float wsum[4][2048];
    const int tid = threadIdx.x, lane = tid & 63, w = tid >> 6;
    const int blk = blockIdx.x;
    float cs[8][4];
#pragma unroll
    for (int j = 0; j < 8; ++j) { cs[j][0]=0.f; cs[j][1]=0.f; cs[j][2]=0.f; cs[j][3]=0.f; }
#pragma unroll
    for (int i = 0; i < 4; ++i) {
        const int r = blk*16 + w*4 + i;
        const float4* xr = (const float4*)(x + (size_t)r * D_DIM);
        float4 v[8]; float s = 0.f, ss = 0.f;
#pragma unroll
        for (int j = 0; j < 8; ++j) {
            v[j] = xr[j*64 + lane];
            s  += v[j].x + v[j].y + v[j].z + v[j].w;
            ss += v[j].x*v[j].x + v[j].y*v[j].y + v[j].z*v[j].z + v[j].w*v[j].w;
        }
#pragma unroll
        for (int off = 32; off; off >>= 1) { s += __shfl_xor(s, off); ss += __shfl_xor(ss, off); }
        const float mean = s * (1.f/2048.f);
        const float var  = ss * (1.f/2048.f) - mean*mean;
        const float rstd = rsqrtf(var + 1e-5f);
#pragma unroll
        for (int j = 0; j < 8; ++j) {
            cs[j][0] += (v[j].x - mean)*rstd;
            cs[j][1] += (v[j].y - mean)*rstd;
            cs[j][2] += (v[j].z - mean)*rstd;
            cs[j][3] += (v[j].w - mean)*rstd;
        }
    }
#pragma unroll
    for (int j = 0; j < 8; ++j) {
        float4 t4; t4.x=cs[j][0]; t4.y=cs[j][1]; t4.z=cs[j][2]; t4.w=cs[j][3];
        *(float4*)&wsum[w][(j*64+lane)*4] = t4;
    }
    __syncthreads();
#pragma unroll
    for (int p = 0; p < 2; ++p) {
        const int c4 = p*256 + tid;
        float4 a0 = *(const float4*)&wsum[0][c4*4];
        float4 a1 = *(const float4*)&wsum[1][c4*4];
        float4 a2 = *(const float4*)&wsum[2][c4*4];
        float4 a3 = *(const float4*)&wsum[3][c4*4];
        float4 r4; r4.x=a0.x+a1.x+a2.x+a3.x; r4.y=a0.y+a1.y+a2.y+a3.y;
        r4.z=a0.z+a1.z+a2.z+a3.z; r4.w=a0.w+a1.w+a2.w+a3.w;
        *(float4*)(partial + (size_t)blk*D_DIM + c4*4) = r4;
    }
}

// ---------------- Kernel 3a: reduce partial DIRECTLY (+gamma/beta) + q/k proj + l2norm
// 64 blocks: one per (b,t,which). Per thread (c,hh): sum 128 partial rows.
__global__ __launch_bounds__(256) void k_qk(const float* __restrict__ partial,
        const float* __restrict__ gamma, const float* __restrict__ beta,
        const float* __restrict__ Wq, const float* __restrict__ bq,
        const float* __restrict__ Wk, const float* __restrict__ bk,
        float* __restrict__ qkbuf)
{
    __shared__ float red2[2][128];
    __shared__ float rrow[128];
    __shared__ float yrow[128];
    __shared__ float ssum[2];
    const int g = blockIdx.x;
    const int b = g >> 5, t = (g >> 1) & 15, which = g & 1;
    const float* W    = which ? Wk : Wq;
    const float* bias = which ? bk : bq;
    const int tid = threadIdx.x, lane = tid & 63, w = tid >> 6;
    {
        const int c = tid & 127, hh = tid >> 7;
        const float* p = partial + (size_t)(b*256 + hh*128)*2048 + t*128 + c;
        float s = 0.f;
#pragma unroll 8
        for (int r = 0; r < 128; ++r) s += p[(size_t)r*2048];
        red2[hh][c] = s;
    }
    __syncthreads();
    if (tid < 128)
        rrow[tid] = gamma[t*128 + tid] * (red2[0][tid] + red2[1][tid]) * (1.f/4096.f)
                  + beta[t*128 + tid];
    __syncthreads();
    const int c0 = (lane & 15) * 8;
#pragma unroll
    for (int r = 0; r < 8; ++r) {
        const int d = r*16 + w*4 + (lane >> 4);
        const float4 w0 = *(const float4*)(W + d*128 + c0);
        const float4 w1 = *(const float4*)(W + d*128 + c0 + 4);
        float acc = w0.x*rrow[c0]   + w0.y*rrow[c0+1] + w0.z*rrow[c0+2] + w0.w*rrow[c0+3]
                  + w1.x*rrow[c0+4] + w1.y*rrow[c0+5] + w1.z*rrow[c0+6] + w1.w*rrow[c0+7];
#pragma unroll
        for (int off = 1; off <= 8; off <<= 1) acc += __shfl_xor(acc, off);
        if ((lane & 15) == 0) yrow[d] = acc + bias[d];
    }
    __syncthreads();
    if (tid < 128) {
        float v = yrow[tid];
        float sq = v * v;
#pragma unroll
        for (int off = 32; off; off >>= 1) sq += __shfl_xor(sq, off);
        if (lane == 0) ssum[tid >> 6] = sq;
    }
    __syncthreads();
    if (tid < 128) {
        const float rn = 1.f / fmaxf(sqrtf(ssum[0] + ssum[1]), 1e-12f);
        qkbuf[(which*32 + b*16 + t)*128 + tid] = yrow[tid] * rn;
    }
}

// ---------------- Kernel 3b: scores + top-4 -> routes [B][T][K]
__global__ __launch_bounds__(256) void k_score(const float* __restrict__ qkbuf,
                                               int* __restrict__ routes)
{
    __shared__ float qk_s[8192];
    __shared__ float sc[2][16][16];
    const int tid = threadIdx.x;
    for (int i = tid; i < 2048; i += 256)
        *(float4*)&qk_s[i*4] = *(const float4*)(qkbuf + i*4);
    __syncthreads();
#pragma unroll
    for (int p = 0; p < 2; ++p) {
        const int e = p*256 + tid;
        const int b = e >> 8, t = (e >> 4) & 15, u = e & 15;
        const float4* qr = (const float4*)&qk_s[(b*16 + t)*128];
        const float4* kr = (const float4*)&qk_s[(32 + b*16 + u)*128];
        float s = 0.f;
#pragma unroll
        for (int c = 0; c < 32; ++c) {
            float4 a = qr[c], bb = kr[c];
            s += a.x*bb.x + a.y*bb.y + a.z*bb.z + a.w*bb.w;
        }
        sc[b][t][u] = (u == t) ? -1e9f : s;
    }
    __syncthreads();
    if (tid < 32) {
        const int b = tid >> 4, t = tid & 15;
        unsigned taken = 0;
        for (int kk = 0; kk < 4; ++kk) {
            float bv = -3.0e38f; int bu = 0;
            for (int u = 0; u < 16; ++u) {
                if ((taken >> u) & 1u) continue;
                const float v = sc[b][t][u];
                if (v > bv) { bv = v; bu = u; }   // strict > = lax.top_k tie-break
            }
            taken |= (1u << bu);
            routes[(b*16 + t)*4 + kk] = bu;
        }
    }
}

// ---------------- Kernel 5: fused LN + gather + MLP + residual.
// Round-14 geometry (1024 blocks x 4 waves, BM=128, T-MAJOR m=t*8+s, 64.5KB LDS,
// 2 blocks/CU) with REORDERED K-loops: reads-first against sealed buffers (no
// wait at top), lgkm(0)+mid-barrier (WAR seal), stage UNDER MFMA, bottom
// vmcnt(0)+barrier (seal next buffer). ks=9 stages W2(0) into the w2L alias.
// Seal rule (round-13 lesson): cooperatively-staged buffers are read only
// after a [vmcnt(0)-all -> barrier] pair; xnL/srcT are resident (read anytime).
__global__ __launch_bounds__(256, 2) void k_mlp(
    const float* __restrict__ x,
    const float* __restrict__ gamma, const float* __restrict__ beta,
    const bf16_t* __restrict__ W1t, const bf16_t* __restrict__ W2t,
    const float* __restrict__ b1, const float* __restrict__ b2,
    const int* __restrict__ routes, float* __restrict__ out)
{
    __shared__ char lds[65856];
    int* srcT = (int*)(lds + 65536);
    char* xnL = lds;                 // 32KB  (GEMM1, resident)
    char* w1L = lds + 32768;         // 32KB  (GEMM1, staged per ks)
    char* hL  = lds;                 // 32KB  (GEMM2, aliases xnL)
    char* w2L = lds + 32768;         // 16KB  (GEMM2, aliases w1L)

    const int tid = threadIdx.x, lane = tid & 63, w = tid >> 6;
    const int blk = blockIdx.x;
    const int b  = blk >> 9;
    const int s0 = (blk & 511) * 8;

    const int l15 = lane & 15;
    const int khi = lane >> 4;          // 0..3
    const int sl7 = l15 & 7;
    const int thi = l15 >> 3;

    if (tid < 80) {
        const int t = tid / 5, j = tid % 5;
        srcT[tid] = (j == 0) ? t : routes[(b*NT + t)*KW + (j-1)];
    }

    // prologue: stage W1(0) -> w1L (lands while LN runs)
    {
        const bf16_t* w1g = W1t + lane*8;
#pragma unroll
        for (int it = 0; it < 8; ++it) {
            const int q = it*4 + w;
            gload_lds16(w1g + q*512, w1L + q*1024);
        }
    }

    // ---- Stage 1: LayerNorm 8 rows (2/wave) -> xnL (bf16, swizzled) ----
#pragma unroll
    for (int i = 0; i < 2; ++i) {
        const int sl = w*2 + i;
        const float4* xr = (const float4*)(x + ((size_t)(b*S_LEN + s0 + sl))*D_DIM);
        float4 v[8]; float s = 0.f, ss = 0.f;
#pragma unroll
        for (int q = 0; q < 4; ++q) {
#pragma unroll
            for (int p = 0; p < 2; ++p) {
                float4 vv = xr[(q*64 + lane)*2 + p];
                v[q*2+p] = vv;
                s  += vv.x + vv.y + vv.z + vv.w;
                ss += vv.x*vv.x + vv.y*vv.y + vv.z*vv.z + vv.w*vv.w;
            }
        }
#pragma unroll
        for (int off = 32; off; off >>= 1) { s += __shfl_xor(s, off); ss += __shfl_xor(ss, off); }
        const float mean = s * (1.f/2048.f);
        const float var  = ss * (1.f/2048.f) - mean*mean;
        const float rstd = rsqrtf(var + 1e-5f);
        const float4* g4 = (const float4*)gamma;
        const float4* e4 = (const float4*)beta;
#pragma unroll
        for (int q = 0; q < 4; ++q) {
            const int gch = q*64 + lane;
            const float4 va = v[q*2], vb = v[q*2+1];
            const float4 ga = g4[gch*2], gb = g4[gch*2+1];
            const float4 ea = e4[gch*2], eb = e4[gch*2+1];
            bf16x8 o;
            o[0] = (bf16_t)((va.x - mean)*rstd*ga.x + ea.x);
            o[1] = (bf16_t)((va.y - mean)*rstd*ga.y + ea.y);
            o[2] = (bf16_t)((va.z - mean)*rstd*ga.z + ea.z);
            o[3] = (bf16_t)((va.w - mean)*rstd*ga.w + ea.w);
            o[4] = (bf16_t)((vb.x - mean)*rstd*gb.x + eb.x);
            o[5] = (bf16_t)((vb.y - mean)*rstd*gb.y + eb.y);
            o[6] = (bf16_t)((vb.z - mean)*rstd*gb.z + eb.z);
            o[7] = (bf16_t)((vb.w - mean)*rstd*gb.w + eb.w);
            const int u  = gch >> 4;
            const int cw = gch & 15;
            *(bf16x8*)(xnL + sl*4096 + u*256 + ((cw ^ sl) << 4)) = o;
        }
    }

    const int nbase = w * 64;
    f32x4 acc[4][8];
#pragma unroll
    for (int i = 0; i < 4; ++i)
#pragma unroll
        for (int j = 0; j < 8; ++j) acc[i][j] = (f32x4){0.f,0.f,0.f,0.f};

    // pre-loop seal: W1(0) landed (all waves) + xnL/srcT visible
    asm volatile("s_waitcnt vmcnt(0)" ::: "memory");
    __syncthreads();

    // ---- GEMM1: reads-first, stage-under-MFMA ----
    for (int ks = 0; ks < 10; ++ks) {
        int us[8];
#pragma unroll
        for (int mf = 0; mf < 8; ++mf)
            us[mf] = srcT[(mf*2 + thi)*5 + (ks >> 1)];

        bf16x8 af0[4], af1[4], bfr[8];
#pragma unroll
        for (int nf = 0; nf < 4; ++nf) {
            const int n = nbase + nf*16 + l15;
            af0[nf] = *(const bf16x8*)(w1L + n*128 + ((khi*16)      ^ ((n & 7) << 4)));
            af1[nf] = *(const bf16x8*)(w1L + n*128 + ((64 + khi*16) ^ ((n & 7) << 4)));
        }
        {
            const int co0 = ((((ks & 1)*8 + khi) ^ sl7) << 4);
#pragma unroll
            for (int mf = 0; mf < 8; ++mf)
                bfr[mf] = *(const bf16x8*)(xnL + sl7*4096 + us[mf]*256 + co0);
        }
        asm volatile("s_waitcnt lgkmcnt(0)" ::: "memory");  // own reads retired
        __builtin_amdgcn_s_barrier();                        // ALL reads retired -> w1L free

        if (ks < 9) {        // stage W1(ks+1) under the MFMAs
            const bf16_t* w1g = W1t + (ks + 1)*16384 + lane*8;
#pragma unroll
            for (int it = 0; it < 8; ++it) {
                const int q = it*4 + w;
                gload_lds16(w1g + q*512, w1L + q*1024);
            }
        } else {             // stage W2(0) into w2L alias (reads sealed above)
            const bf16_t* w2g = W2t + lane*8;
#pragma unroll
            for (int it = 0; it < 4; ++it) {
                const int q = it*4 + w;
                gload_lds16(w2g + q*512, w2L + q*1024);
            }
        }

#pragma unroll
        for (int nf = 0; nf < 4; ++nf)
#pragma unroll
            for (int mf = 0; mf < 8; ++mf)
                acc[nf][mf] = __builtin_amdgcn_mfma_f32_16x16x32_bf16(
                    af0[nf], bfr[mf], acc[nf][mf], 0, 0, 0);
        {
            const int co1 = ((((ks & 1)*8 + 4 + khi) ^ sl7) << 4);
#pragma unroll
            for (int mf = 0; mf < 8; ++mf)
                bfr[mf] = *(const bf16x8*)(xnL + sl7*4096 + us[mf]*256 + co1);
        }
#pragma unroll
        for (int nf = 0; nf < 4; ++nf)
#pragma unroll
            for (int mf = 0; mf < 8; ++mf)
                acc[nf][mf] = __builtin_amdgcn_mfma_f32_16x16x32_bf16(
                    af1[nf], bfr[mf], acc[nf][mf], 0, 0, 0);

        asm volatile("s_waitcnt vmcnt(0)" ::: "memory");     // own stage landed
        __builtin_amdgcn_s_barrier();                        // buffer sealed
    }

    // ---- epilogue 1: bias + gelu -> packed bf16 regs ----
    bf16x4 hreg[4][8];
#pragma unroll
    for (int nf = 0; nf < 4; ++nf) {
        const int k0 = nbase + nf*16 + khi*4;
        const float4 b1v = *(const float4*)(b1 + k0);
#pragma unroll
        for (int mf = 0; mf < 8; ++mf) {
#pragma unroll
            for (int r = 0; r < 4; ++r) {
                const float z = acc[nf][mf][r] + ((const float*)&b1v)[r];
                const float uu = z + 0.044715f * z * z * z;
                const float gl = z / (1.f + __expf(-1.5957691216f * uu));
                hreg[nf][mf][r] = (bf16_t)gl;
            }
        }
    }

    // phase A: waves 0,1 write h cols 0..127 into hL (xnL dead after ks=9 bottom barrier)
    const int colb = (nbase & 127) + khi*4;
    if (w < 2) {
#pragma unroll
        for (int nf = 0; nf < 4; ++nf) {
            const int cb2 = (colb + nf*16) * 2;
#pragma unroll
            for (int mf = 0; mf < 8; ++mf) {
                const int m = mf*16 + l15;
                *(bf16x4*)(hL + m*256 + (cb2 ^ ((m & 7) << 4))) = hreg[nf][mf];
            }
        }
    }
    asm volatile("s_waitcnt lgkmcnt(0)" ::: "memory");
    __builtin_amdgcn_s_barrier();     // hL-A visible; w2L(0) sealed at ks=9 bottom

    // ---- GEMM2: reads-first, stage-under-MFMA ----
    f32x4 acc2[2][8];
#pragma unroll
    for (int i = 0; i < 2; ++i)
#pragma unroll
        for (int j = 0; j < 8; ++j) acc2[i][j] = (f32x4){0.f,0.f,0.f,0.f};

    for (int ks2 = 0; ks2 < 4; ++ks2) {
        if (ks2 == 2) {
            if (w >= 2) {   // phase B: waves 2,3 write h cols 128..255 (A-reads sealed @ks2=1 mid)
#pragma unroll
                for (int nf = 0; nf < 4; ++nf) {
                    const int cb2 = (colb + nf*16) * 2;
#pragma unroll
                    for (int mf = 0; mf < 8; ++mf) {
                        const int m = mf*16 + l15;
                        *(bf16x4*)(hL + m*256 + (cb2 ^ ((m & 7) << 4))) = hreg[nf][mf];
                    }
                }
            }
            asm volatile("s_waitcnt lgkmcnt(0)" ::: "memory");
            __builtin_amdgcn_s_barrier();
        }
        bf16x8 ah0[8], ah1[8], bw0[2], bw1[2];
#pragma unroll
        for (int mf = 0; mf < 8; ++mf) {
            const int m = mf*16 + l15;
            const int x0 = (((ks2 & 1)*64 +      khi*8) * 2) ^ ((m & 7) << 4);
            const int x1 = (((ks2 & 1)*64 + 32 + khi*8) * 2) ^ ((m & 7) << 4);
            ah0[mf] = *(const bf16x8*)(hL + m*256 + x0);
            ah1[mf] = *(const bf16x8*)(hL + m*256 + x1);
        }
#pragma unroll
        for (int nf = 0; nf < 2; ++nf) {
            const int n2 = w*32 + nf*16 + l15;
            bw0[nf] = *(const bf16x8*)(w2L + n2*128 + (((     khi*8) * 2) ^ ((n2 & 7) << 4)));
            bw1[nf] = *(const bf16x8*)(w2L + n2*128 + (((32 + khi*8) * 2) ^ ((n2 & 7) << 4)));
        }
        asm volatile("s_waitcnt lgkmcnt(0)" ::: "memory");
        __builtin_amdgcn_s_barrier();       // all w2L reads retired -> overwritable
        if (ks2 < 3) {                       // stage W2(ks2+1) under MFMA
            const bf16_t* w2g = W2t + (ks2 + 1)*8192 + lane*8;
#pragma unroll
            for (int it = 0; it < 4; ++it) {
                const int q = it*4 + w;
                gload_lds16(w2g + q*512, w2L + q*1024);
            }
        }
#pragma unroll
        for (int nf = 0; nf < 2; ++nf)
#pragma unroll
            for (int mf = 0; mf < 8; ++mf)
                acc2[nf][mf] = __builtin_amdgcn_mfma_f32_16x16x32_bf16(
                    ah0[mf], bw0[nf], acc2[nf][mf], 0, 0, 0);
#pragma unroll
        for (int nf = 0; nf < 2; ++nf)
#pragma unroll
            for (int mf = 0; mf < 8; ++mf)
                acc2[nf][mf] = __builtin_amdgcn_mfma_f32_16x16x32_bf16(
                    ah1[mf], bw1[nf], acc2[nf][mf], 0, 0, 0);
        asm volatile("s_waitcnt vmcnt(0)" ::: "memory");
        __builtin_amdgcn_s_barrier();       // w2L(ks2+1) sealed
    }

    // ---- epilogue 2: + b2 + residual x.  T-MAJOR decode: t = m>>3, s = m&7.
#pragma unroll
    for (int nf = 0; nf < 2; ++nf) {
        const int n2 = w*32 + nf*16 + l15;
        const float b2v = b2[n2];
#pragma unroll
        for (int mf = 0; mf < 8; ++mf) {
            const int mb = mf*16 + khi*4;
#pragma unroll
            for (int r = 0; r < 4; ++r) {
                const int m = mb + r;
                const int s = s0 + (m & 7);
                const int t = m >> 3;
                const size_t o = ((size_t)(b*S_LEN + s))*D_DIM + t*TD + n2;
                out[o] = x[o] + acc2[nf][mf][r] + b2v;
            }
        }
    }
}

extern "C" void kernel_launch(void* const* d_in, const int* in_sizes, int n_in,
                              void* d_out, int out_size, void* d_ws, size_t ws_size,
                              hipStream_t stream) {
    const float* x     = (const float*)d_in[0];
    const float* gamma = (const float*)d_in[1];
    const float* beta  = (const float*)d_in[2];
    const float* Wq    = (const float*)d_in[3];
    const float* bq    = (const float*)d_in[4];
    const float* Wk    = (const float*)d_in[5];
    const float* bk    = (const float*)d_in[6];
    const float* W1    = (const float*)d_in[7];
    const float* b1    = (const float*)d_in[8];
    const float* W2    = (const float*)d_in[9];
    const float* b2    = (const float*)d_in[10];
    float* out = (float*)d_out;

    char* ws = (char*)d_ws;
    float*  partial  = (float*) ws;                   // 4,194,304 B [512][2048]
    float*  qkbuf    = (float*) (ws + 4194304);       //    32,768 B
    int*    routes   = (int*)   (ws + 4227072);       //       512 B
    bf16_t* W1t      = (bf16_t*)(ws + 4227584);       //   327,680 B
    bf16_t* W2t      = (bf16_t*)(ws + 4555264);       //    65,536 B

    k_pre<<<1280, 256, 0, stream>>>(x, W1, W2, partial, W1t, W2t);
    k_qk<<<64, 256, 0, stream>>>(partial, gamma, beta, Wq, bq, Wk, bk, qkbuf);
    k_score<<<1, 256, 0, stream>>>(qkbuf, routes);
    k_mlp<<<1024, 256, 0, stream>>>(x, gamma, beta, W1t, W2t, b1, b2, routes, out);
}

// Round 16
// 120.345 us; speedup vs baseline: 1.0344x; 1.0344x over previous
//
#include <hip/hip_runtime.h>
#include <stdint.h>

#define S_LEN 4096
#define D_DIM 2048
#define NT 16
#define TD 128
#define KW 4
#define CTX 640
#define HID 256

typedef __bf16 bf16_t;
typedef __bf16 bf16x8 __attribute__((ext_vector_type(8)));
typedef __bf16 bf16x4 __attribute__((ext_vector_type(4)));
typedef float f32x4 __attribute__((ext_vector_type(4)));
typedef unsigned int u32;
typedef u32 __attribute__((address_space(1))) gu32;
typedef u32 __attribute__((address_space(3))) lu32;

__device__ __forceinline__ void gload_lds16(const void* g, void* l) {
    __builtin_amdgcn_global_load_lds((const gu32*)g, (lu32*)l, 16, 0, 0);
}

// ---------------- Kernel 1 (merged): blocks 0..511 = row stats + tile-sum
// partials; blocks 512..1279 = W1/W2 pre-tile/pre-swizzle.
__global__ __launch_bounds__(256) void k_pre(const float* __restrict__ x,
        const float* __restrict__ W1, const float* __restrict__ W2,
        float* __restrict__ partial, bf16_t* __restrict__ W1t, bf16_t* __restrict__ W2t)
{
    if (blockIdx.x >= 512) {   // ---- prep part ----
        const int g = (blockIdx.x - 512) * 256 + threadIdx.x;
        if (g < 10*256*64) {
            const int ks = g >> 14, rem = g & 16383, n = rem >> 6, kk = rem & 63;
            const int kkl = ((kk << 1) ^ ((n & 7) << 4)) >> 1;
            W1t[g] = (bf16_t)W1[n*CTX + ks*64 + kkl];
        } else if (g < 10*256*64 + 4*128*64) {
            const int gg = g - 10*256*64;
            const int ks = gg >> 13, rem = gg & 8191, n = rem >> 6, kk = rem & 63;
            const int kkl = ((kk << 1) ^ ((n & 7) << 4)) >> 1;
            W2t[gg] = (bf16_t)W2[n*HID + ks*64 + kkl];
        }
        return;
    }
    // ---- stats part ----
    __shared__ float wsum[4][2048];
    const int tid = threadIdx.x, lane = tid & 63, w = tid >> 6;
    const int blk = blockIdx.x;
    float cs[8][4];
#pragma unroll
    for (int j = 0; j < 8; ++j) { cs[j][0]=0.f; cs[j][1]=0.f; cs[j][2]=0.f; cs[j][3]=0.f; }
#pragma unroll
    for (int i = 0; i < 4; ++i) {
        const int r = blk*16 + w*4 + i;
        const float4* xr = (const float4*)(x + (size_t)r * D_DIM);
        float4 v[8]; float s = 0.f, ss = 0.f;
#pragma unroll
        for (int j = 0; j < 8; ++j) {
            v[j] = xr[j*64 + lane];
            s  += v[j].x + v[j].y + v[j].z + v[j].w;
            ss += v[j].x*v[j].x + v[j].y*v[j].y + v[j].z*v[j].z + v[j].w*v[j].w;
        }
#pragma unroll
        for (int off = 32; off; off >>= 1) { s += __shfl_xor(s, off); ss += __shfl_xor(ss, off); }
        const float mean = s * (1.f/2048.f);
        const float var  = ss * (1.f/2048.f) - mean*mean;
        const float rstd = rsqrtf(var + 1e-5f);
#pragma unroll
        for (int j = 0; j < 8; ++j) {
            cs[j][0] += (v[j].x - mean)*rstd;
            cs[j][1] += (v[j].y - mean)*rstd;
            cs[j][2] += (v[j].z - mean)*rstd;
            cs[j][3] += (v[j].w - mean)*rstd;
        }
    }
#pragma unroll
    for (int j = 0; j < 8; ++j) {
        float4 t4; t4.x=cs[j][0]; t4.y=cs[j][1]; t4.z=cs[j][2]; t4.w=cs[j][3];
        *(float4*)&wsum[w][(j*64+lane)*4] = t4;
    }
    __syncthreads();
#pragma unroll
    for (int p = 0; p < 2; ++p) {
        const int c4 = p*256 + tid;
        float4 a0 = *(const float4*)&wsum[0][c4*4];
        float4 a1 = *(const float4*)&wsum[1][c4*4];
        float4 a2 = *(const float4*)&wsum[2][c4*4];
        float4 a3 = *(const float4*)&wsum[3][c4*4];
        float4 r4; r4.x=a0.x+a1.x+a2.x+a3.x; r4.y=a0.y+a1.y+a2.y+a3.y;
        r4.z=a0.z+a1.z+a2.z+a3.z; r4.w=a0.w+a1.w+a2.w+a3.w;
        *(float4*)(partial + (size_t)blk*D_DIM + c4*4) = r4;
    }
}

// ---------------- Kernel 3a: reduce partial DIRECTLY (+gamma/beta) + q/k proj + l2norm
// 64 blocks: one per (b,t,which). Per thread (c,hh): sum 128 partial rows.
__global__ __launch_bounds__(256) void k_qk(const float* __restrict__ partial,
        const float* __restrict__ gamma, const float* __restrict__ beta,
        const float* __restrict__ Wq, const float* __restrict__ bq,
        const float* __restrict__ Wk, const float* __restrict__ bk,
        float* __restrict__ qkbuf)
{
    __shared__ float red2[2][128];
    __shared__ float rrow[128];
    __shared__ float yrow[128];
    __shared__ float ssum[2];
    const int g = blockIdx.x;
    const int b = g >> 5, t = (g >> 1) & 15, which = g & 1;
    const float* W    = which ? Wk : Wq;
    const float* bias = which ? bk : bq;
    const int tid = threadIdx.x, lane = tid & 63, w = tid >> 6;
    {
        const int c = tid & 127, hh = tid >> 7;
        const float* p = partial + (size_t)(b*256 + hh*128)*2048 + t*128 + c;
        float s = 0.f;
#pragma unroll 8
        for (int r = 0; r < 128; ++r) s += p[(size_t)r*2048];
        red2[hh][c] = s;
    }
    __syncthreads();
    if (tid < 128)
        rrow[tid] = gamma[t*128 + tid] * (red2[0][tid] + red2[1][tid]) * (1.f/4096.f)
                  + beta[t*128 + tid];
    __syncthreads();
    const int c0 = (lane & 15) * 8;
#pragma unroll
    for (int r = 0; r < 8; ++r) {
        const int d = r*16 + w*4 + (lane >> 4);
        const float4 w0 = *(const float4*)(W + d*128 + c0);
        const float4 w1 = *(const float4*)(W + d*128 + c0 + 4);
        float acc = w0.x*rrow[c0]   + w0.y*rrow[c0+1] + w0.z*rrow[c0+2] + w0.w*rrow[c0+3]
                  + w1.x*rrow[c0+4] + w1.y*rrow[c0+5] + w1.z*rrow[c0+6] + w1.w*rrow[c0+7];
#pragma unroll
        for (int off = 1; off <= 8; off <<= 1) acc += __shfl_xor(acc, off);
        if ((lane & 15) == 0) yrow[d] = acc + bias[d];
    }
    __syncthreads();
    if (tid < 128) {
        float v = yrow[tid];
        float sq = v * v;
#pragma unroll
        for (int off = 32; off; off >>= 1) sq += __shfl_xor(sq, off);
        if (lane == 0) ssum[tid >> 6] = sq;
    }
    __syncthreads();
    if (tid < 128) {
        const float rn = 1.f / fmaxf(sqrtf(ssum[0] + ssum[1]), 1e-12f);
        qkbuf[(which*32 + b*16 + t)*128 + tid] = yrow[tid] * rn;
    }
}

// ---------------- Kernel 3b: scores + top-4 -> routes [B][T][K]
__global__ __launch_bounds__(256) void k_score(const float* __restrict__ qkbuf,
                                               int* __restrict__ routes)
{
    __shared__ float qk_s[8192];
    __shared__ float sc[2][16][16];
    const int tid = threadIdx.x;
    for (int i = tid; i < 2048; i += 256)
        *(float4*)&qk_s[i*4] = *(const float4*)(qkbuf + i*4);
    __syncthreads();
#pragma unroll
    for (int p = 0; p < 2; ++p) {
        const int e = p*256 + tid;
        const int b = e >> 8, t = (e >> 4) & 15, u = e & 15;
        const float4* qr = (const float4*)&qk_s[(b*16 + t)*128];
        const float4* kr = (const float4*)&qk_s[(32 + b*16 + u)*128];
        float s = 0.f;
#pragma unroll
        for (int c = 0; c < 32; ++c) {
            float4 a = qr[c], bb = kr[c];
            s += a.x*bb.x + a.y*bb.y + a.z*bb.z + a.w*bb.w;
        }
        sc[b][t][u] = (u == t) ? -1e9f : s;
    }
    __syncthreads();
    if (tid < 32) {
        const int b = tid >> 4, t = tid & 15;
        unsigned taken = 0;
        for (int kk = 0; kk < 4; ++kk) {
            float bv = -3.0e38f; int bu = 0;
            for (int u = 0; u < 16; ++u) {
                if ((taken >> u) & 1u) continue;
                const float v = sc[b][t][u];
                if (v > bv) { bv = v; bu = u; }   // strict > = lax.top_k tie-break
            }
            taken |= (1u << bu);
            routes[(b*16 + t)*4 + kk] = bu;
        }
    }
}

// ---------------- Kernel 5: fused LN + gather + MLP + residual.
// Round-14 geometry (1024 blocks x 4 waves, BM=128, T-MAJOR m=t*8+s, 64.5KB LDS,
// 2 blocks/CU) with REORDERED K-loops: reads-first against sealed buffers (no
// wait at top), lgkm(0)+mid-barrier (WAR seal), stage UNDER MFMA, bottom
// vmcnt(0)+barrier (seal next buffer). ks=9 stages W2(0) into the w2L alias.
// Seal rule (round-13 lesson): cooperatively-staged buffers are read only
// after a [vmcnt(0)-all -> barrier] pair; xnL/srcT are resident (read anytime).
__global__ __launch_bounds__(256, 2) void k_mlp(
    const float* __restrict__ x,
    const float* __restrict__ gamma, const float* __restrict__ beta,
    const bf16_t* __restrict__ W1t, const bf16_t* __restrict__ W2t,
    const float* __restrict__ b1, const float* __restrict__ b2,
    const int* __restrict__ routes, float* __restrict__ out)
{
    __shared__ char lds[65856];
    int* srcT = (int*)(lds + 65536);
    char* xnL = lds;                 // 32KB  (GEMM1, resident)
    char* w1L = lds + 32768;         // 32KB  (GEMM1, staged per ks)
    char* hL  = lds;                 // 32KB  (GEMM2, aliases xnL)
    char* w2L = lds + 32768;         // 16KB  (GEMM2, aliases w1L)

    const int tid = threadIdx.x, lane = tid & 63, w = tid >> 6;
    const int blk = blockIdx.x;
    const int b  = blk >> 9;
    const int s0 = (blk & 511) * 8;

    const int l15 = lane & 15;
    const int khi = lane >> 4;          // 0..3
    const int sl7 = l15 & 7;
    const int thi = l15 >> 3;

    if (tid < 80) {
        const int t = tid / 5, j = tid % 5;
        srcT[tid] = (j == 0) ? t : routes[(b*NT + t)*KW + (j-1)];
    }

    // prologue: stage W1(0) -> w1L (lands while LN runs)
    {
        const bf16_t* w1g = W1t + lane*8;
#pragma unroll
        for (int it = 0; it < 8; ++it) {
            const int q = it*4 + w;
            gload_lds16(w1g + q*512, w1L + q*1024);
        }
    }

    // ---- Stage 1: LayerNorm 8 rows (2/wave) -> xnL (bf16, swizzled) ----
#pragma unroll
    for (int i = 0; i < 2; ++i) {
        const int sl = w*2 + i;
        const float4* xr = (const float4*)(x + ((size_t)(b*S_LEN + s0 + sl))*D_DIM);
        float4 v[8]; float s = 0.f, ss = 0.f;
#pragma unroll
        for (int q = 0; q < 4; ++q) {
#pragma unroll
            for (int p = 0; p < 2; ++p) {
                float4 vv = xr[(q*64 + lane)*2 + p];
                v[q*2+p] = vv;
                s  += vv.x + vv.y + vv.z + vv.w;
                ss += vv.x*vv.x + vv.y*vv.y + vv.z*vv.z + vv.w*vv.w;
            }
        }
#pragma unroll
        for (int off = 32; off; off >>= 1) { s += __shfl_xor(s, off); ss += __shfl_xor(ss, off); }
        const float mean = s * (1.f/2048.f);
        const float var  = ss * (1.f/2048.f) - mean*mean;
        const float rstd = rsqrtf(var + 1e-5f);
        const float4* g4 = (const float4*)gamma;
        const float4* e4 = (const float4*)beta;
#pragma unroll
        for (int q = 0; q < 4; ++q) {
            const int gch = q*64 + lane;
            const float4 va = v[q*2], vb = v[q*2+1];
            const float4 ga = g4[gch*2], gb = g4[gch*2+1];
            const float4 ea = e4[gch*2], eb = e4[gch*2+1];
            bf16x8 o;
            o[0] = (bf16_t)((va.x - mean)*rstd*ga.x + ea.x);
            o[1] = (bf16_t)((va.y - mean)*rstd*ga.y + ea.y);
            o[2] = (bf16_t)((va.z - mean)*rstd*ga.z + ea.z);
            o[3] = (bf16_t)((va.w - mean)*rstd*ga.w + ea.w);
            o[4] = (bf16_t)((vb.x - mean)*rstd*gb.x + eb.x);
            o[5] = (bf16_t)((vb.y - mean)*rstd*gb.y + eb.y);
            o[6] = (bf16_t)((vb.z - mean)*rstd*gb.z + eb.z);
            o[7] = (bf16_t)((vb.w - mean)*rstd*gb.w + eb.w);
            const int u  = gch >> 4;
            const int cw = gch & 15;
            *(bf16x8*)(xnL + sl*4096 + u*256 + ((cw ^ sl) << 4)) = o;
        }
    }

    const int nbase = w * 64;
    f32x4 acc[4][8];
#pragma unroll
    for (int i = 0; i < 4; ++i)
#pragma unroll
        for (int j = 0; j < 8; ++j) acc[i][j] = (f32x4){0.f,0.f,0.f,0.f};

    // pre-loop seal: W1(0) landed (all waves) + xnL/srcT visible
    asm volatile("s_waitcnt vmcnt(0)" ::: "memory");
    __syncthreads();

    // ---- GEMM1: reads-first, stage-under-MFMA ----
    for (int ks = 0; ks < 10; ++ks) {
        int us[8];
#pragma unroll
        for (int mf = 0; mf < 8; ++mf)
            us[mf] = srcT[(mf*2 + thi)*5 + (ks >> 1)];

        bf16x8 af0[4], af1[4], bfr[8];
#pragma unroll
        for (int nf = 0; nf < 4; ++nf) {
            const int n = nbase + nf*16 + l15;
            af0[nf] = *(const bf16x8*)(w1L + n*128 + ((khi*16)      ^ ((n & 7) << 4)));
            af1[nf] = *(const bf16x8*)(w1L + n*128 + ((64 + khi*16) ^ ((n & 7) << 4)));
        }
        {
            const int co0 = ((((ks & 1)*8 + khi) ^ sl7) << 4);
#pragma unroll
            for (int mf = 0; mf < 8; ++mf)
                bfr[mf] = *(const bf16x8*)(xnL + sl7*4096 + us[mf]*256 + co0);
        }
        asm volatile("s_waitcnt lgkmcnt(0)" ::: "memory");  // own reads retired
        __builtin_amdgcn_s_barrier();                        // ALL reads retired -> w1L free

        if (ks < 9) {        // stage W1(ks+1) under the MFMAs
            const bf16_t* w1g = W1t + (ks + 1)*16384 + lane*8;
#pragma unroll
            for (int it = 0; it < 8; ++it) {
                const int q = it*4 + w;
                gload_lds16(w1g + q*512, w1L + q*1024);
            }
        } else {             // stage W2(0) into w2L alias (reads sealed above)
            const bf16_t* w2g = W2t + lane*8;
#pragma unroll
            for (int it = 0; it < 4; ++it) {
                const int q = it*4 + w;
                gload_lds16(w2g + q*512, w2L + q*1024);
            }
        }

#pragma unroll
        for (int nf = 0; nf < 4; ++nf)
#pragma unroll
            for (int mf = 0; mf < 8; ++mf)
                acc[nf][mf] = __builtin_amdgcn_mfma_f32_16x16x32_bf16(
                    af0[nf], bfr[mf], acc[nf][mf], 0, 0, 0);
        {
            const int co1 = ((((ks & 1)*8 + 4 + khi) ^ sl7) << 4);
#pragma unroll
            for (int mf = 0; mf < 8; ++mf)
                bfr[mf] = *(const bf16x8*)(xnL + sl7*4096 + us[mf]*256 + co1);
        }
#pragma unroll
        for (int nf = 0; nf < 4; ++nf)
#pragma unroll
            for (int mf = 0; mf < 8; ++mf)
                acc[nf][mf] = __builtin_amdgcn_mfma_f32_16x16x32_bf16(
                    af1[nf], bfr[mf], acc[nf][mf], 0, 0, 0);

        asm volatile("s_waitcnt vmcnt(0)" ::: "memory");     // own stage landed
        __builtin_amdgcn_s_barrier();                        // buffer sealed
    }

    // ---- epilogue 1: bias + gelu -> packed bf16 regs ----
    bf16x4 hreg[4][8];
#pragma unroll
    for (int nf = 0; nf < 4; ++nf) {
        const int k0 = nbase + nf*16 + khi*4;
        const float4 b1v = *(const float4*)(b1 + k0);
#pragma unroll
        for (int mf = 0; mf < 8; ++mf) {
#pragma unroll
            for (int r = 0; r < 4; ++r) {
                const float z = acc[nf][mf][r] + ((const float*)&b1v)[r];
                const float uu = z + 0.044715f * z * z * z;
                const float gl = z / (1.f + __expf(-1.5957691216f * uu));
                hreg[nf][mf][r] = (bf16_t)gl;
            }
        }
    }

    // phase A: waves 0,1 write h cols 0..127 into hL (xnL dead after ks=9 bottom barrier)
    const int colb = (nbase & 127) + khi*4;
    if (w < 2) {
#pragma unroll
        for (int nf = 0; nf < 4; ++nf) {
            const int cb2 = (colb + nf*16) * 2;
#pragma unroll
            for (int mf = 0; mf < 8; ++mf) {
                const int m = mf*16 + l15;
                *(bf16x4*)(hL + m*256 + (cb2 ^ ((m & 7) << 4))) = hreg[nf][mf];
            }
        }
    }
    asm volatile("s_waitcnt lgkmcnt(0)" ::: "memory");
    __builtin_amdgcn_s_barrier();     // hL-A visible; w2L(0) sealed at ks=9 bottom

    // ---- GEMM2: reads-first, stage-under-MFMA ----
    f32x4 acc2[2][8];
#pragma unroll
    for (int i = 0; i < 2; ++i)
#pragma unroll
        for (int j = 0; j < 8; ++j) acc2[i][j] = (f32x4){0.f,0.f,0.f,0.f};

    for (int ks2 = 0; ks2 < 4; ++ks2) {
        if (ks2 == 2) {
            if (w >= 2) {   // phase B: waves 2,3 write h cols 128..255 (A-reads sealed @ks2=1 mid)
#pragma unroll
                for (int nf = 0; nf < 4; ++nf) {
                    const int cb2 = (colb + nf*16) * 2;
#pragma unroll
                    for (int mf = 0; mf < 8; ++mf) {
                        const int m = mf*16 + l15;
                        *(bf16x4*)(hL + m*256 + (cb2 ^ ((m & 7) << 4))) = hreg[nf][mf];
                    }
                }
            }
            asm volatile("s_waitcnt lgkmcnt(0)" ::: "memory");
            __builtin_amdgcn_s_barrier();
        }
        bf16x8 ah0[8], ah1[8], bw0[2], bw1[2];
#pragma unroll
        for (int mf = 0; mf < 8; ++mf) {
            const int m = mf*16 + l15;
            const int x0 = (((ks2 & 1)*64 +      khi*8) * 2) ^ ((m & 7) << 4);
            const int x1 = (((ks2 & 1)*64 + 32 + khi*8) * 2) ^ ((m & 7) << 4);
            ah0[mf] = *(const bf16x8*)(hL + m*256 + x0);
            ah1[mf] = *(const bf16x8*)(hL + m*256 + x1);
        }
#pragma unroll
        for (int nf = 0; nf < 2; ++nf) {
            const int n2 = w*32 + nf*16 + l15;
            bw0[nf] = *(const bf16x8*)(w2L + n2*128 + (((     khi*8) * 2) ^ ((n2 & 7) << 4)));
            bw1[nf] = *(const bf16x8*)(w2L + n2*128 + (((32 + khi*8) * 2) ^ ((n2 & 7) << 4)));
        }
        asm volatile("s_waitcnt lgkmcnt(0)" ::: "memory");
        __builtin_amdgcn_s_barrier();       // all w2L reads retired -> overwritable
        if (ks2 < 3) {                       // stage W2(ks2+1) under MFMA
            const bf16_t* w2g = W2t + (ks2 + 1)*8192 + lane*8;
#pragma unroll
            for (int it = 0; it < 4; ++it) {
                const int q = it*4 + w;
                gload_lds16(w2g + q*512, w2L + q*1024);
            }
        }
#pragma unroll
        for (int nf = 0; nf < 2; ++nf)
#pragma unroll
            for (int mf = 0; mf < 8; ++mf)
                acc2[nf][mf] = __builtin_amdgcn_mfma_f32_16x16x32_bf16(
                    ah0[mf], bw0[nf], acc2[nf][mf], 0, 0, 0);
#pragma unroll
        for (int nf = 0; nf < 2; ++nf)
#pragma unroll
            for (int mf = 0; mf < 8; ++mf)
                acc2[nf][mf] = __builtin_amdgcn_mfma_f32_16x16x32_bf16(
                    ah1[mf], bw1[nf], acc2[nf][mf], 0, 0, 0);
        asm volatile("s_waitcnt vmcnt(0)" ::: "memory");
        __builtin_amdgcn_s_barrier();       // w2L(ks2+1) sealed
    }

    // ---- epilogue 2: + b2 + residual x.  T-MAJOR decode: t = m>>3, s = m&7.
#pragma unroll
    for (int nf = 0; nf < 2; ++nf) {
        const int n2 = w*32 + nf*16 + l15;
        const float b2v = b2[n2];
#pragma unroll
        for (int mf = 0; mf < 8; ++mf) {
            const int mb = mf*16 + khi*4;
#pragma unroll
            for (int r = 0; r < 4; ++r) {
                const int m = mb + r;
                const int s = s0 + (m & 7);
                const int t = m >> 3;
                const size_t o = ((size_t)(b*S_LEN + s))*D_DIM + t*TD + n2;
                out[o] = x[o] + acc2[nf][mf][r] + b2v;
            }
        }
    }
}

extern "C" void kernel_launch(void* const* d_in, const int* in_sizes, int n_in,
                              void* d_out, int out_size, void* d_ws, size_t ws_size,
                              hipStream_t stream) {
    const float* x     = (const float*)d_in[0];
    const float* gamma = (const float*)d_in[1];
    const float* beta  = (const float*)d_in[2];
    const float* Wq    = (const float*)d_in[3];
    const float* bq    = (const float*)d_in[4];
    const float* Wk    = (const float*)d_in[5];
    const float* bk    = (const float*)d_in[6];
    const float* W1    = (const float*)d_in[7];
    const float* b1    = (const float*)d_in[8];
    const float* W2    = (const float*)d_in[9];
    const float* b2    = (const float*)d_in[10];
    float* out = (float*)d_out;

    char* ws = (char*)d_ws;
    float*  partial  = (float*) ws;                   // 4,194,304 B [512][2048]
    float*  qkbuf    = (float*) (ws + 4194304);       //    32,768 B
    int*    routes   = (int*)   (ws + 4227072);       //       512 B
    bf16_t* W1t      = (bf16_t*)(ws + 4227584);       //   327,680 B
    bf16_t* W2t      = (bf16_t*)(ws + 4555264);       //    65,536 B

    k_pre<<<1280, 256, 0, stream>>>(x, W1, W2, partial, W1t, W2t);
    k_qk<<<64, 256, 0, stream>>>(partial, gamma, beta, Wq, bq, Wk, bk, qkbuf);
    k_score<<<1, 256, 0, stream>>>(qkbuf, routes);
    k_mlp<<<1024, 256, 0, stream>>>(x, gamma, beta, W1t, W2t, b1, b2, routes, out);
}